// Round 5
// baseline (909.636 us; speedup 1.0000x reference)
//
#include <hip/hip_runtime.h>
#include <hip/hip_bf16.h>
#include <stdint.h>

#define NINF -100000.0f

constexpr int Bn = 64, Tn = 512, Hn = 768, Nn = 25;

// ---------------- dtype detection ----------------
// flags[0] = 1 if float tensors are bf16, 0 if f32
// flags[1] = bool storage width in bytes (1/4/8)
// flags[2] = padding_index value
__global__ __launch_bounds__(64) void k_detect(const void* emb, const void* mask,
                                               const void* padidx, int* flags) {
    int lane = threadIdx.x;
    const uint16_t* e16 = (const uint16_t*)emb;
    uint16_t v = e16[lane];
    int ex = (v >> 7) & 0xFF;
    bool sane = (ex >= 100 && ex <= 140);
    unsigned long long ball = __ballot(sane);
    int cnt = __popcll(ball);
    if (lane == 0) {
        flags[0] = (cnt >= 56) ? 1 : 0;
        const int* mw = (const int*)mask;
        int w0 = mw[0];
        int w1 = mw[1];
        int bw;
        if ((unsigned)w0 > 1u) bw = 1;
        else if (w0 == 1 && w1 == 0) bw = 8;
        else bw = 4;
        flags[1] = bw;
        flags[2] = ((const int*)padidx)[0];
    }
}

__device__ inline float ldf(const void* p, int i, bool isbf) {
    if (isbf) return __bfloat162float(((const __hip_bfloat16*)p)[i]);
    return ((const float*)p)[i];
}
__device__ inline int ldb(const void* p, int i, int bw) {
    if (bw == 1) return (int)((const uint8_t*)p)[i];
    if (bw == 8) return ((const int*)p)[2 * i];
    return ((const int*)p)[i];
}

// ---------------- convert constants to canonical f32 forms in ws ----------------
__global__ __launch_bounds__(256) void k_convert(
    const void* W, const void* bv, const void* trans, const void* startt, const void* endt,
    const void* mask, const void* sc, const void* ec, const void* tc,
    const int* flags, float* wsWf,
    float* wsb, float* wsstart, float* wsend, float* wsscm, float* wsecm,
    float* wstrans, float* wstc, int* lengths)
{
    bool isbf = flags[0] != 0;
    int bw = flags[1];
    int gid = blockIdx.x * blockDim.x + threadIdx.x;
    int gsz = gridDim.x * blockDim.x;
    for (int i = gid; i < Hn * Nn; i += gsz) wsWf[i] = ldf(W, i, isbf);
    for (int i = gid; i < Nn; i += gsz) {
        wsb[i]     = ldf(bv, i, isbf);
        wsstart[i] = ldf(startt, i, isbf);
        wsend[i]   = ldf(endt, i, isbf);
        wsscm[i]   = ldb(sc, i, bw) ? 0.0f : NINF;
        wsecm[i]   = ldb(ec, i, bw) ? 0.0f : NINF;
    }
    for (int i = gid; i < Nn * Nn; i += gsz) {
        wstrans[i] = ldf(trans, i, isbf);
        wstc[i]    = ldb(tc, i, bw) ? 0.0f : NINF;
    }
    for (int r = gid; r < Bn; r += gsz) {
        int s = 0;
        for (int t = 0; t < Tn; t++) s += (ldb(mask, r * Tn + t, bw) ? 1 : 0);
        lengths[r] = s;
    }
}

// ---------------- logits: strict np.einsum replication ----------------
// One thread per row. acc[j] accumulated as sequential f32 (mul, add) over
// h = 0..767 ascending — c_einsum generic-strided-loop order, NO fma.
// 256 blocks x 128 threads; block covers 128 rows (all in one batch).
__global__ __launch_bounds__(128) void k_gemm(
    const void* embv, const float* wsWf, const float* wsb, const float* wstrans,
    const float* wsstart, const float* wsend,
    const int* lengths, const int* flags,
    float* logitsF, void* out)
{
    __shared__ float etile[128][65];   // 128 rows x 64-h chunk, padded
    __shared__ float wtile[64][26];    // 64-h chunk x 25 cols
    __shared__ float lgs[128][26];
    __shared__ float s_trans[625];
    __shared__ float s_start[25], s_end[25], s_b[25];

    int tid  = threadIdx.x;
    int row0 = blockIdx.x * 128;
    int row  = row0 + tid;
    bool isbf = flags[0] != 0;

    for (int i = tid; i < 625; i += 128) s_trans[i] = wstrans[i];
    if (tid < 25) { s_start[tid] = wsstart[tid]; s_end[tid] = wsend[tid]; s_b[tid] = wsb[tid]; }

    float acc[25];
#pragma unroll
    for (int j = 0; j < 25; j++) acc[j] = 0.0f;

    for (int c = 0; c < 12; c++) {
        __syncthreads();
        // stage 128 rows x 64 h (coalesced over hh within each row)
        if (isbf) {
            const __hip_bfloat16* ep = (const __hip_bfloat16*)embv;
#pragma unroll 8
            for (int it = 0; it < 64; it++) {
                int idx = it * 128 + tid;
                int hh = idx & 63, r = idx >> 6;
                etile[r][hh] = __bfloat162float(ep[(size_t)(row0 + r) * Hn + c * 64 + hh]);
            }
        } else {
            const float* ep = (const float*)embv;
#pragma unroll 8
            for (int it = 0; it < 64; it++) {
                int idx = it * 128 + tid;
                int hh = idx & 63, r = idx >> 6;
                etile[r][hh] = ep[(size_t)(row0 + r) * Hn + c * 64 + hh];
            }
        }
        // stage W chunk
        for (int i = tid; i < 1600; i += 128) {
            int hh = i / 25, j = i - hh * 25;
            wtile[hh][j] = wsWf[(size_t)(c * 64 + hh) * 25 + j];
        }
        __syncthreads();
        {
#pragma clang fp contract(off)
            for (int hh = 0; hh < 64; hh++) {
                float e = etile[tid][hh];
#pragma unroll
                for (int j = 0; j < 25; j++) {
                    acc[j] = acc[j] + e * wtile[hh][j];
                }
            }
        }
    }

    // logits = einsum + b  (one f32 add, ref association)
    {
#pragma clang fp contract(off)
#pragma unroll
        for (int j = 0; j < 25; j++) {
            float lg = acc[j] + s_b[j];
            lgs[tid][j] = lg;
            logitsF[(size_t)row * 25 + j] = lg;
        }
    }
    __syncthreads();

    // lp epilogue
    int bidx = row0 >> 9;
    int len  = lengths[bidx];
    int last = len - 1;
    for (int r = 0; r < 128; r++) {
        int rw = row0 + r;
        int t = rw & 511;
        bool isfirst = (t == 0);
        bool islast  = (t == last);
        {
#pragma clang fp contract(off)
            for (int e = tid; e < 625; e += 128) {
                int i = e / 25;
                int j = e - i * 25;
                float lg = lgs[r][j];
                float v;
                if (isfirst) v = s_start[j] + lg;
                else         v = lg + s_trans[e];
                if (islast)  v += s_end[j];
                size_t o = (size_t)rw * 625 + e;
                if (isbf) ((__hip_bfloat16*)out)[o] = __float2bfloat16(v);
                else      ((float*)out)[o] = v;
            }
        }
    }
}

// ---------------- Viterbi: 1 wave per batch, exact f32 replication ----------------
// Lane j < 25 owns column j; lanes 25..63 shadow column 0 and never write.
__global__ __launch_bounds__(64) void k_viterbi(
    const float* logitsF, const float* wstrans, const float* wstc,
    const float* wsstart, const float* wsend, const float* wsscm, const float* wsecm,
    const int* lengths, const int* flags, void* out)
{
    __shared__ float   chunk[1600];   // 64 steps x 25 logits
    __shared__ float   aT[32];
    __shared__ uint8_t bp[511][32];
    __shared__ uint8_t tags[512];

    int b = blockIdx.x;
    int L = threadIdx.x;
    bool act = (L < 25);
    int j = act ? L : 0;
    int len = lengths[b];
    int last = len - 1;
    bool isbf = flags[0] != 0;
    int padv = flags[2];

    float trr[25], tcc[25];
#pragma unroll
    for (int i = 0; i < 25; i++) {
        trr[i] = wstrans[i * 25 + j];
        tcc[i] = wstc[i * 25 + j];
    }
    float endj = wsend[j];
    float ecmj = wsecm[j];

    const float* lgb = logitsF + (size_t)b * (Tn * Nn);

    // alpha0[j] = (start[j] + logits[b,0,j]) + scm[j]
    float areg;
    {
#pragma clang fp contract(off)
        areg = act ? ((wsstart[j] + lgb[j]) + wsscm[j]) : -3.0e38f;
    }

    for (int c = 0; c < 8; c++) {
        __syncthreads();
        for (int k2 = L; k2 < 1600; k2 += 64) chunk[k2] = lgb[c * 1600 + k2];
        __syncthreads();
        for (int s = 0; s < 64; s++) {
            int t = c * 64 + s;            // uniform across lanes
            if (t == 0) continue;
            float m = -3.0e38f;
            int mi = 0;
            {
#pragma clang fp contract(off)
                if (t >= len) {
#pragma unroll
                    for (int i = 0; i < 25; i++) {
                        float ai = __shfl(areg, i, 64);
                        float v = (i == j) ? 0.0f : NINF;
                        float sc2 = ai + v;
                        if (sc2 > m) { m = sc2; mi = i; }
                    }
                } else if (t == last) {
                    float Lg = chunk[s * 25 + j];
#pragma unroll
                    for (int i = 0; i < 25; i++) {
                        float ai = __shfl(areg, i, 64);
                        float v = (((Lg + trr[i]) + endj) + tcc[i]) + ecmj;
                        float sc2 = ai + v;
                        if (sc2 > m) { m = sc2; mi = i; }
                    }
                } else {
                    float Lg = chunk[s * 25 + j];
#pragma unroll
                    for (int i = 0; i < 25; i++) {
                        float ai = __shfl(areg, i, 64);
                        float v = (Lg + trr[i]) + tcc[i];
                        float sc2 = ai + v;
                        if (sc2 > m) { m = sc2; mi = i; }
                    }
                }
            }
            areg = act ? m : -3.0e38f;
            if (act) bp[t - 1][j] = (uint8_t)mi;
        }
    }

    if (act) aT[j] = areg;
    __syncthreads();
    if (L == 0) {
        float m = aT[0];
        int mi = 0;
        for (int jx = 1; jx < 25; jx++) {
            if (aT[jx] > m) { m = aT[jx]; mi = jx; }
        }
        int tag = mi;
        tags[511] = (uint8_t)tag;
        for (int k2 = 510; k2 >= 0; k2--) {
            tag = bp[k2][tag];
            tags[k2] = (uint8_t)tag;
        }
    }
    __syncthreads();

    size_t base = 20480000ull;  // B*T*N*N
    for (int t = L; t < 512; t += 64) {
        float val = (t < len) ? (float)tags[t] : (float)padv;
        size_t o = base + (size_t)b * 512 + t;
        if (isbf) ((__hip_bfloat16*)out)[o] = __float2bfloat16(val);
        else      ((float*)out)[o] = val;
    }
}

extern "C" void kernel_launch(void* const* d_in, const int* in_sizes, int n_in,
                              void* d_out, int out_size, void* d_ws, size_t ws_size,
                              hipStream_t stream) {
    const void* emb  = d_in[0];
    const void* W    = d_in[1];
    const void* bv   = d_in[2];
    const void* tr   = d_in[3];
    const void* st   = d_in[4];
    const void* en   = d_in[5];
    const void* mask = d_in[6];
    const void* sc   = d_in[7];
    const void* ec   = d_in[8];
    const void* tc   = d_in[9];
    const void* pad  = d_in[10];

    char* ws = (char*)d_ws;
    int*    flags    = (int*)ws;             // 64 B
    int*    lengths  = (int*)(ws + 64);      // 256 B
    float*  wsb      = (float*)(ws + 384);
    float*  wsstart  = (float*)(ws + 512);
    float*  wsend    = (float*)(ws + 640);
    float*  wsscm    = (float*)(ws + 768);
    float*  wsecm    = (float*)(ws + 896);
    float*  wstrans  = (float*)(ws + 1024);  // 2500 B
    float*  wstc     = (float*)(ws + 3584);  // 2500 B
    float*  wsWf     = (float*)(ws + 6144);  // 76800 B -> ends 82944
    float*  logitsF  = (float*)(ws + 82944); // 3276800 B -> ends ~3.36 MB

    k_detect<<<1, 64, 0, stream>>>(emb, mask, pad, flags);
    k_convert<<<64, 256, 0, stream>>>(W, bv, tr, st, en, mask, sc, ec, tc, flags,
                                      wsWf, wsb, wsstart, wsend, wsscm, wsecm,
                                      wstrans, wstc, lengths);
    k_gemm<<<256, 128, 0, stream>>>(emb, wsWf, wsb, wstrans, wsstart, wsend,
                                    lengths, flags, logitsF, d_out);
    k_viterbi<<<64, 64, 0, stream>>>(logitsF, wstrans, wstc, wsstart, wsend,
                                     wsscm, wsecm, lengths, flags, d_out);
}